// Round 22
// baseline (107.972 us; speedup 1.0000x reference)
//
#include <hip/hip_runtime.h>
#include <hip/hip_bf16.h>

#define BATCH 16
#define SEQ   2048
#define HD    128
#define TB    64            // proj tile rows
#define QB2   128           // attn q-tile rows
#define KB2   128           // attn kv-tile rows
#define NTB   (SEQ/KB2)     // 16 kv tiles per batch
#define PLANE ((size_t)BATCH*SEQ*HD)   // shorts per ws plane

typedef __attribute__((ext_vector_type(8)))  short bf16x8;
typedef __attribute__((ext_vector_type(4)))  float f32x4;
typedef __attribute__((ext_vector_type(16))) float f32x16;

#define MFMA(a,b,c)   __builtin_amdgcn_mfma_f32_16x16x32_bf16(a,b,c,0,0,0)
#define MFMA32(a,b,c) __builtin_amdgcn_mfma_f32_32x32x16_bf16(a,b,c,0,0,0)

__device__ __forceinline__ short f2bf(float f){
  union{float f; unsigned u;} v; v.f = f;
  unsigned r = (v.u + 0x7FFFu + ((v.u>>16)&1u))>>16;
  return (short)r;
}
__device__ __forceinline__ unsigned packbf(float lo, float hi){
  return ((unsigned)(unsigned short)f2bf(hi) << 16) | (unsigned short)f2bf(lo);
}
__device__ __forceinline__ bf16x8 pack8(f32x4 a, f32x4 b){
  bf16x8 r;
  r[0]=f2bf(a[0]); r[1]=f2bf(a[1]); r[2]=f2bf(a[2]); r[3]=f2bf(a[3]);
  r[4]=f2bf(b[0]); r[5]=f2bf(b[1]); r[6]=f2bf(b[2]); r[7]=f2bf(b[3]);
  return r;
}
__device__ __forceinline__ bf16x8 ldfrag(const float* base, size_t eo){
  const float* p = base + eo;
  return pack8(*(const f32x4*)p, *(const f32x4*)(p+4));
}
__device__ __forceinline__ bf16x8 mkfrag(unsigned w0, unsigned w1,
                                         unsigned w2, unsigned w3){
  union{ unsigned u[4]; bf16x8 v; } t;
  t.u[0]=w0; t.u[1]=w1; t.u[2]=w2; t.u[3]=w3;
  return t.v;
}

// ---------------- kernel 0: W fp32 -> bf16 once ------------------------------
__global__ __launch_bounds__(256)
void wconv_kernel(const float* __restrict__ Wq, const float* __restrict__ Wk,
                  const float* __restrict__ Wv, short* __restrict__ wb)
{
  int i = (blockIdx.x*256 + threadIdx.x)*8;
  const float* src = (i < 16384) ? Wq : (i < 32768 ? Wk : Wv);
  int off = i & 16383;
  f32x4 a = *(const f32x4*)(src + off);
  f32x4 b = *(const f32x4*)(src + off + 4);
  *(bf16x8*)(wb + i) = pack8(a, b);
}

// ---------------- kernel 1: projections -> ws (bf16) -------------------------
// z=0: Qh row-major. z=1: Kh 32KB images [128 rows]: chunk(r,c8)=r*16+(c8^(r&7)).
// z=2: Vh^T 32KB images [d][c8 0..15]: chunk(d,c8)=d*16+(c8^(d&7)).
__global__ __launch_bounds__(256)
void proj_kernel(const float* __restrict__ q, const float* __restrict__ k,
                 const float* __restrict__ v,
                 const float* __restrict__ bq, const float* __restrict__ bk,
                 const float* __restrict__ bv,
                 const short* __restrict__ wb, short* __restrict__ ws)
{
  __shared__ __align__(16) short T[TB*136];    // [s_local][h] bounce (z<2)
  __shared__ __align__(16) short VT[HD*72];    // [h][s_local] bounce (z==2)

  const int z = blockIdx.y;
  const float* x  = z==0 ? q  : (z==1 ? k  : v);
  const float* bb = z==0 ? bq : (z==1 ? bk : bv);
  const short* W  = wb + (size_t)z*HD*HD;

  const int tid = threadIdx.x;
  const int w = tid>>6, l = tid&63, li = l&15, g = l>>4;
  const int bx = blockIdx.x;                   // 64-row tile id (b = bx>>5)
  const int rowbase = bx*TB + w*16;

  bf16x8 afr[4];
  const float* xr = x + (size_t)(rowbase+li)*HD + g*8;
  #pragma unroll
  for (int ks=0; ks<4; ks++) afr[ks] = ldfrag(xr, (size_t)ks*32);

  f32x4 acc[8];
  #pragma unroll
  for (int ct=0; ct<8; ct++) acc[ct] = (f32x4){0.f,0.f,0.f,0.f};
  #pragma unroll
  for (int ct=0; ct<8; ct++){
    #pragma unroll
    for (int ks=0; ks<4; ks++){
      bf16x8 bfr = *(const bf16x8*)(W + (size_t)(ct*16+li)*HD + ks*32 + g*8);
      acc[ct] = MFMA(afr[ks], bfr, acc[ct]);
    }
  }

  const int img  = (bx>>1);                    // 128-row image id
  const int half = bx & 1;                     // which 64-row half

  if (z < 2){
    #pragma unroll
    for (int ct=0; ct<8; ct++){
      float bias = bb[ct*16+li];
      #pragma unroll
      for (int r=0; r<4; r++)
        T[(w*16+g*4+r)*136 + ct*16+li] = f2bf(acc[ct][r] + bias);
    }
    __syncthreads();
    if (z == 0){
      short* dst = ws + (size_t)bx*TB*HD;
      #pragma unroll
      for (int it=0; it<4; it++){
        int c = tid + it*256, row = c>>4, c8 = c&15;
        *(bf16x8*)(dst + row*HD + c8*8) = *(const bf16x8*)&T[row*136 + c8*8];
      }
    } else {
      short* dst = ws + PLANE + (size_t)img*16384;
      #pragma unroll
      for (int it=0; it<4; it++){
        int c = tid + it*256, row = c>>4, c8 = c&15;
        int r128 = half*64 + row;
        int chunk = r128*16 + (c8 ^ (r128&7));
        *(bf16x8*)(dst + chunk*8) = *(const bf16x8*)&T[row*136 + c8*8];
      }
    }
  } else {
    #pragma unroll
    for (int ct=0; ct<8; ct++){
      float bias = bb[ct*16+li];
      #pragma unroll
      for (int r=0; r<4; r++)
        VT[(ct*16+li)*72 + w*16+g*4+r] = f2bf(acc[ct][r] + bias);
    }
    __syncthreads();
    short* dst = ws + 2*PLANE + (size_t)img*16384;
    const int d = tid>>1, hf = tid&1;
    #pragma unroll
    for (int j=0; j<4; j++){
      int c8l = hf*4 + j;
      int c8g = half*8 + c8l;
      int chunk = d*16 + (c8g ^ (d&7));
      *(bf16x8*)(dst + chunk*8) = *(const bf16x8*)&VT[d*72 + c8l*8];
    }
  }
}

// ---------------- kernel 2: causal flash attention (32x32 MFMA) --------------
// 8 waves = 4 q-strips (32 rows) x 2 k-halves (64). Each wave reads ONLY its
// K/V half (2x operand reuse via 32x32x16). Softmax rows lane-local
// (C: col=lane&31=q, row=(reg&3)+8*(reg>>2)+4*(lane>>5) per m74/m101);
// cross-half merge via small LDS (m,l) exchange; P stays in registers
// (shfl_xor(32) redistribution). O per-half, merged in epilogue via KVL.
__global__ __launch_bounds__(512, 2)
void attn_kernel(const short* __restrict__ ws, float* __restrict__ out)
{
  __shared__ __align__(16) short KVL[2][32768]; // [buf][K 32KB | V 32KB]
  __shared__ float sm[4][2][2][32];             // [strip][h][{m,l}][q]
  __shared__ float scl_l[4][2][32];             // per-strip O-rescale bcast

  const int bid  = blockIdx.x;                  // 256 blocks
  const int xcd  = bid & 7, slot = bid >> 3;
  const int b    = xcd*2 + (slot >> 4);
  const int qt   = slot & 15;

  const int tid = threadIdx.x;
  const int w = tid>>6, l = tid&63;
  const int s = w & 3, h = w >> 2;              // q-strip, k-half
  const int lq = l & 31, h5 = l >> 5;

  const short* Qw    = ws;
  const short* KimgB = ws + PLANE   + (size_t)b*NTB*16384;
  const short* VimgB = ws + 2*PLANE + (size_t)b*NTB*16384;

  const size_t qbase = (size_t)b*SEQ + qt*QB2;
  const float sc = 0.088388347648318447f;       // 1/sqrt(128)
  const int qg = (int)(qt*QB2) + s*32 + lq;     // this lane's q row (softmax)

  // Q fragments: B-operand (d16 x q32): lane: q=lq, d = ks*16 + h5*8 + j
  bf16x8 qfr[8];
  #pragma unroll
  for (int ks=0; ks<8; ks++)
    qfr[ks] = *(const bf16x8*)&Qw[(qbase + s*32 + lq)*HD + ks*16 + h5*8];

  f32x16 oacc[4];
  #pragma unroll
  for (int db=0; db<4; db++) oacc[db] = (f32x16)(0.f);
  float m_run = -1e30f, l_run = 0.f;

  bf16x8 stg[8];
  #define LOADT(kt_) do{                                                    \
    const short* sK = KimgB + (size_t)(kt_)*16384;                          \
    const short* sV = VimgB + (size_t)(kt_)*16384;                          \
    _Pragma("unroll")                                                       \
    for (int j=0;j<4;j++) stg[j]   = *(const bf16x8*)(sK + (tid + j*512)*8);\
    _Pragma("unroll")                                                       \
    for (int j=0;j<4;j++) stg[4+j] = *(const bf16x8*)(sV + (tid + j*512)*8);\
  }while(0)
  #define WRT(nb_) do{                                                     \
    short* dK = &KVL[nb_][0];                                              \
    short* dV = &KVL[nb_][16384];                                          \
    _Pragma("unroll")                                                      \
    for (int j=0;j<4;j++) *(bf16x8*)(dK + (tid+j*512)*8) = stg[j];         \
    _Pragma("unroll")                                                      \
    for (int j=0;j<4;j++) *(bf16x8*)(dV + (tid+j*512)*8) = stg[4+j];       \
  }while(0)

  LOADT(0); WRT(0); __syncthreads();
  int cur = 0;

  for (int kt=0; kt<=qt; kt++){
    const bool pre = (kt < qt);
    if (pre) LOADT(kt+1);

    const short* KL = &KVL[cur][0];
    const short* VL = &KVL[cur][16384];

    // ---- QK^T: S[k 64(half)][q 32(strip)]; A=K(32k x16d), B=Q(16d x32q)
    f32x16 sacc[2];
    sacc[0] = (f32x16)(0.f); sacc[1] = (f32x16)(0.f);
    #pragma unroll
    for (int ct=0; ct<2; ct++){
      const int r = h*64 + ct*32 + lq;          // K row
      #pragma unroll
      for (int ks=0; ks<8; ks++){
        const int chunk = r*16 + ((2*ks + h5) ^ (r&7));
        bf16x8 kfr = *(const bf16x8*)&KL[chunk*8];
        sacc[ct] = MFMA32(kfr, qfr[ks], sacc[ct]);
      }
    }

    // ---- mask+scale; lane-local softmax over 32 vals + 1 shfl pair-merge
    float sv[2][16];
    float pm = -1e30f;
    const bool diag = (kt == qt);
    #pragma unroll
    for (int ct=0; ct<2; ct++){
      #pragma unroll
      for (int r=0; r<16; r++){
        float x = sacc[ct][r]*sc;
        if (diag){
          int k_loc = h*64 + ct*32 + (r&3) + 8*(r>>2) + 4*h5;
          if (kt*KB2 + k_loc > qg - (int)(qt*QB2) + (int)(qt*KB2)) x = -1e30f;
        }
        sv[ct][r] = x;
        pm = fmaxf(pm, x);
      }
    }
    pm = fmaxf(pm, __shfl_xor(pm, 32));
    float psum = 0.f;
    #pragma unroll
    for (int ct=0; ct<2; ct++){
      #pragma unroll
      for (int r=0; r<16; r++){
        float p = __expf(sv[ct][r] - pm);
        sv[ct][r] = p;
        psum += p;
      }
    }
    psum += __shfl_xor(psum, 32);

    if (l < 32){ sm[s][h][0][lq] = pm; sm[s][h][1][lq] = psum; }
    __syncthreads();                            // barrier 1: m/l exchange
    float pm_p = sm[s][h^1][0][lq];
    float ps_p = sm[s][h^1][1][lq];
    float m_new  = fmaxf(m_run, fmaxf(pm, pm_p));
    float sclq   = __expf(m_run - m_new);
    float pscale = __expf(pm - m_new);
    m_run = m_new;
    l_run = l_run*sclq + psum*pscale;
    (void)ps_p;
    if (l < 32) scl_l[s][h][lq] = sclq;

    // ---- O rescale (per-reg q via LDS broadcast)
    float sclr[16];
    #pragma unroll
    for (int r=0; r<16; r++)
      sclr[r] = scl_l[s][h][(r&3) + 8*(r>>2) + 4*h5];
    #pragma unroll
    for (int db=0; db<4; db++){
      #pragma unroll
      for (int r=0; r<16; r++) oacc[db][r] *= sclr[r];
    }

    // ---- P -> bf16 A-frags in registers (pack + shfl_xor(32))
    #pragma unroll
    for (int ct=0; ct<2; ct++){
      unsigned G[4][2], GX[4][2];
      #pragma unroll
      for (int g2=0; g2<4; g2++){
        #pragma unroll
        for (int p=0; p<2; p++)
          G[g2][p] = packbf(sv[ct][g2*4+2*p]*pscale, sv[ct][g2*4+2*p+1]*pscale);
      }
      #pragma unroll
      for (int g2=0; g2<4; g2++){
        #pragma unroll
        for (int p=0; p<2; p++)
          GX[g2][p] = __shfl_xor((int)G[g2][p], 32);
      }
      bf16x8 pf0 = h5 ? mkfrag(GX[1][0],GX[1][1],G[1][0],G[1][1])
                      : mkfrag(G[0][0],G[0][1],GX[0][0],GX[0][1]);
      bf16x8 pf1 = h5 ? mkfrag(GX[3][0],GX[3][1],G[3][0],G[3][1])
                      : mkfrag(G[2][0],G[2][1],GX[2][0],GX[2][1]);
      // ---- PV: A=P(32q x16k), B=V(16k x32d)
      #pragma unroll
      for (int ksp=0; ksp<2; ksp++){
        bf16x8 pf = ksp ? pf1 : pf0;
        #pragma unroll
        for (int db=0; db<4; db++){
          const int d = db*32 + lq;
          const int c8 = h*8 + ct*4 + ksp*2 + h5;
          const int chunk = d*16 + (c8 ^ (d&7));
          bf16x8 vfr = *(const bf16x8*)&VL[chunk*8];
          oacc[db] = MFMA32(pf, vfr, oacc[db]);
        }
      }
    }

    if (pre) WRT(cur^1);
    __syncthreads();                            // barrier 2: buffer swap
    cur ^= 1;
  } // kt

  // ---- epilogue: cross-half O sum via KVL, divide by l_tot, fp32 store
  if (l < 32) sm[s][h][1][lq] = l_run;
  float* Obuf = (float*)&KVL[0][0];             // 64KB region (free now)
  if (h == 1){
    #pragma unroll
    for (int db=0; db<4; db++){
      #pragma unroll
      for (int r=0; r<16; r++){
        int qr = (r&3) + 8*(r>>2) + 4*h5;
        Obuf[s*4096 + qr*128 + db*32 + lq] = oacc[db][r];
      }
    }
  }
  __syncthreads();
  if (h == 0){
    float lt[16];
    #pragma unroll
    for (int r=0; r<16; r++){
      int qr = (r&3) + 8*(r>>2) + 4*h5;
      lt[r] = sm[s][0][1][qr] + sm[s][1][1][qr];
    }
    #pragma unroll
    for (int db=0; db<4; db++){
      #pragma unroll
      for (int r=0; r<16; r++){
        int qr = (r&3) + 8*(r>>2) + 4*h5;
        float o = (oacc[db][r] + Obuf[s*4096 + qr*128 + db*32 + lq]) / lt[r];
        out[(qbase + s*32 + qr)*HD + db*32 + lq] = o;
      }
    }
  }
  #undef LOADT
  #undef WRT
}

// ---------------- launch -----------------------------------------------------
// d_in = [q, k, v, Wq, bq, Wk, bk, Wv, bv, mask] (confirmed R15).
// ws: Qh | Kimg(32KB x 256) | Vimg | Wbf16 (25.3 MB).
extern "C" void kernel_launch(void* const* d_in, const int* in_sizes, int n_in,
                              void* d_out, int out_size, void* d_ws, size_t ws_size,
                              hipStream_t stream)
{
  short* ws = (short*)d_ws;
  short* wb = ws + 3*PLANE;

  wconv_kernel<<<24, 256, 0, stream>>>(
      (const float*)d_in[3], (const float*)d_in[5], (const float*)d_in[7], wb);

  dim3 pg(BATCH*SEQ/TB, 3);
  proj_kernel<<<pg, 256, 0, stream>>>(
      (const float*)d_in[0], (const float*)d_in[1], (const float*)d_in[2],
      (const float*)d_in[4], (const float*)d_in[6], (const float*)d_in[8],
      wb, ws);

  attn_kernel<<<dim3(BATCH*NTB), 512, 0, stream>>>(ws, (float*)d_out);
}